// Round 8
// baseline (286.713 us; speedup 1.0000x reference)
//
#include <hip/hip_runtime.h>

// GCN regressor: 2x (mean-aggregate + linear+ReLU) + per-graph mean + MLP head.
// N=50000 nodes, E=800000 edges, D_IN=128, H1=256, H2=128, G=256.
// R22 = R21 resubmit (R21 bench was an infra failure: container died twice,
// no counters). One defensive change: partE ALIASES aggOut (live ranges
// provably disjoint: partE written in misc[2], consumed in build[3]; aggOut
// first written in agg128[4]) -> workspace back to R20's proven footprint.
// R21: ELL build re-architected - NO per-edge global atomics:
//  - misc partition section: edges binned into 98 node-groups (512 nodes each)
//    via per-block LDS histograms; ONE global atomicAdd per (block,group) run
//    (~25K total, was 800K returning atomics) claims a private contiguous run
//    in the group's fixed-capacity region (GCAP = mean+11sigma, no scan).
//    Writes are run-coalesced, single-writer -> no cross-XCD line bouncing.
//  - build_kernel (98 blocks): per-group LDS atomicAdd-with-return assigns ELL
//    slots; eidx region per group = 64KB single-writer L2-resident; cnt written
//    coalesced from LDS (no cnt memset needed).
//  Rationale (R20 counters): fused count+scatter misc = 55-62us @ VALU 1.4%,
//  HBM 13-17% - pure coherence-point latency + eidx line bouncing (WRITE 58.7MB
//  for 6.4MB of payload; each eidx line written by all 8 XCDs).
// AGGS ARE CLOSED (evidence, 5 structural probes, all 54-58us):
//  - R16 eidx-chain hoist: -2.6us. R17/R18 16B/lane + deep bursts: null.
//  - R19 feature-half XCD sharding: FETCH 173->147MB but time +4%.
//  => bound = random-line SERVICE rate, not HBM bytes/issue depth/footprint.
// Closed experiments (do not revisit):
//  - R6 chunked XCD-local gather: 7x. R8/R9 grid.sync: 2x. R11 agg-GEMM
//    fusion: occupancy collapse. R13 dispatch-merge: neutral. R17
//    launch_bounds(256,8): scratch spill catastrophe (WRITE 25->747MB).
//  - R20 fused per-edge global-atomic ELL build: misc 55-62us latency-bound.

#define NUM_GRAPHS 256
#define MAXDEG 64
#define GSHIFT 9              // 512-node groups
#define GCAP 9216             // per-group edge capacity (mean 8192, sd ~90)

// misc_kernel block partition
#define PART_B0 0
#define PART_NB 256
#define CST_B0 (PART_B0 + PART_NB)
#define CST_NB 512
#define GST_B0 (CST_B0 + CST_NB)
#define GST_NB 64
#define WT1_B0 (GST_B0 + GST_NB)
#define WT1_NB 16
#define WT2_B0 (WT1_B0 + WT1_NB)
#define WT2_NB 32
#define MISC_NB (WT2_B0 + WT2_NB)

typedef __attribute__((ext_vector_type(8))) short bf16x8;
typedef __attribute__((ext_vector_type(4))) float f32x4;

__device__ inline unsigned short f2bf(float f) {  // round-to-nearest-even
    unsigned u = __float_as_uint(f);
    return (unsigned short)((u + 0x7fff + ((u >> 16) & 1)) >> 16);
}
__device__ inline float bflo(unsigned u) { return __uint_as_float(u << 16); }
__device__ inline float bfhi(unsigned u) { return __uint_as_float(u & 0xffff0000u); }

// ---------------- misc: edge partition + gstart + h cast + weight transpose/cast ----------------

__launch_bounds__(256)
__global__ void misc_kernel(const int* __restrict__ dst, const int* __restrict__ src,
                            const int* __restrict__ gids,
                            const float* __restrict__ h,
                            const float* __restrict__ W1, const float* __restrict__ W2,
                            int* __restrict__ cursor, unsigned* __restrict__ partE,
                            int* __restrict__ gstart,
                            unsigned short* __restrict__ hb,
                            unsigned short* __restrict__ Wt1, unsigned short* __restrict__ Wt2,
                            int N, int E) {
    int b = blockIdx.x, tid = threadIdx.x;
    if (b < CST_B0) {  // partition edges into 512-node groups, 2-sweep LDS hist
        __shared__ unsigned lcnt[128];
        __shared__ unsigned gb[128];
        int ngrp = (N + 511) >> GSHIFT;
        int b0 = b - PART_B0;
        int chunk = (E + PART_NB - 1) / PART_NB;
        int ebeg = b0 * chunk;
        int eend = ebeg + chunk; if (eend > E) eend = E;
        for (int i = tid; i < 128; i += 256) lcnt[i] = 0;
        __syncthreads();
        for (int e = ebeg + tid; e < eend; e += 256) {
            int d = __builtin_nontemporal_load(&dst[e]);
            atomicAdd(&lcnt[d >> GSHIFT], 1u);
        }
        __syncthreads();
        for (int g = tid; g < ngrp; g += 256) {
            unsigned c = lcnt[g];
            gb[g] = c ? (unsigned)atomicAdd(&cursor[g], (int)c) : 0u;
            lcnt[g] = 0;
        }
        __syncthreads();
        for (int e = ebeg + tid; e < eend; e += 256) {
            int d = __builtin_nontemporal_load(&dst[e]);
            int s = __builtin_nontemporal_load(&src[e]);
            int g = d >> GSHIFT;
            unsigned r = atomicAdd(&lcnt[g], 1u) + gb[g];
            if (r < GCAP)  // statistically unreachable (cap = mean + 11 sigma)
                __builtin_nontemporal_store(((unsigned)s << GSHIFT) | (unsigned)(d & 511),
                                            &partE[(size_t)g * GCAP + r]);
        }
    } else if (b < GST_B0) {  // cast h -> bf16 (float4 granules)
        int lid = (b - CST_B0) * 256 + tid;
        int total4 = N * 32;
        for (int i = lid; i < total4; i += CST_NB * 256) {
            float4 v = *(const float4*)(h + (size_t)i * 4);
            ushort4 o;
            o.x = f2bf(v.x); o.y = f2bf(v.y); o.z = f2bf(v.z); o.w = f2bf(v.w);
            *(ushort4*)(hb + (size_t)i * 4) = o;
        }
    } else if (b < WT1_B0) {  // graph segment starts (gids sorted)
        int lid = (b - GST_B0) * 256 + tid;
        for (int n = lid; n < N; n += GST_NB * 256) {
            int g = gids[n];
            int gp = (n == 0) ? -1 : gids[n - 1];
            for (int x = gp + 1; x <= g; ++x) gstart[x] = n;
            if (n == N - 1)
                for (int x = g + 1; x <= NUM_GRAPHS; ++x) gstart[x] = N;
        }
    } else if (b < WT2_B0) {  // Wt1[n][k] = bf16(W1[k][n]), K=128
        int lid = (b - WT1_B0) * 256 + tid;
        for (int i = lid; i < 256 * 128; i += WT1_NB * 256)
            Wt1[i] = f2bf(W1[(size_t)(i & 127) * 256 + (i >> 7)]);
    } else {  // Wt2[n][k] = bf16(W2[k][n]), K=256
        int lid = (b - WT2_B0) * 256 + tid;
        for (int i = lid; i < 256 * 256; i += WT2_NB * 256)
            Wt2[i] = f2bf(W2[(size_t)(i & 255) * 256 + (i >> 8)]);
    }
}

// ---------------- ELL build: one block per 512-node group, LDS rank atomics ----------------
// eidx region per group = 64KB, single-writer, L2-resident: no cross-XCD
// bouncing. cnt written coalesced from the LDS histogram (no cnt memset).

__launch_bounds__(256)
__global__ void build_kernel(const unsigned* __restrict__ partE,
                             const int* __restrict__ cursor,
                             int* __restrict__ cnt, unsigned short* __restrict__ eidx,
                             int N) {
    __shared__ unsigned hist[512];
    int g = blockIdx.x, tid = threadIdx.x;
    for (int i = tid; i < 512; i += 256) hist[i] = 0;
    __syncthreads();
    int ec = cursor[g]; if (ec > GCAP) ec = GCAP;
    const unsigned* pe = partE + (size_t)g * GCAP;
    for (int i = tid; i < ec; i += 256) {
        unsigned p = pe[i];
        int dl = (int)(p & 511);
        int s = (int)(p >> GSHIFT);
        unsigned r = atomicAdd(&hist[dl], 1u);
        if (r < MAXDEG)  // statistically unreachable (max deg ~40)
            eidx[((size_t)((g << GSHIFT) + dl)) * MAXDEG + r] = (unsigned short)s;
    }
    __syncthreads();
    for (int i = tid; i < 512; i += 256) {
        int node = (g << GSHIFT) + i;
        if (node < N) cnt[node] = (int)hist[i];
    }
}

// ---------------- mean aggregation: one wave per dst node, ELL edge table ----------------
// R16-exact gather loop (best measured: 54.3us agg256). Coalesced per-lane
// eidx load + shfl broadcast; 4B/8B row loads (economy proven null R17/R18).
// NT output store: consumer (GEMM) streams it; keep L2 for the gather table.

template <int D>
__global__ void agg_mean_bf16_kernel(const unsigned short* __restrict__ feat,
                                     const int* __restrict__ cnt,
                                     const unsigned short* __restrict__ eidx,
                                     unsigned short* __restrict__ out, int N) {
    constexpr int VPL = D / 64;  // 2 or 4
    int wave = blockIdx.x * (blockDim.x >> 6) + (threadIdx.x >> 6);
    int lane = threadIdx.x & 63;
    if (wave >= N) return;
    int deg = cnt[wave];
    int stored = deg > MAXDEG ? MAXDEG : deg;
    const unsigned short* row = eidx + (size_t)wave * MAXDEG;
    int myIdx = (lane < stored) ? (int)row[lane] : 0;

    float acc[VPL];
    #pragma unroll
    for (int i = 0; i < VPL; ++i) acc[i] = 0.0f;

    int j = 0;
    for (; j + 8 <= stored; j += 8) {
        if constexpr (VPL == 2) {
            unsigned v[8];
            #pragma unroll
            for (int u = 0; u < 8; ++u) {
                int s = __shfl(myIdx, j + u, 64);
                v[u] = *(const unsigned*)(feat + (size_t)s * D + lane * 2);
            }
            #pragma unroll
            for (int u = 0; u < 8; ++u) { acc[0] += bflo(v[u]); acc[1] += bfhi(v[u]); }
        } else {
            uint2 v[8];
            #pragma unroll
            for (int u = 0; u < 8; ++u) {
                int s = __shfl(myIdx, j + u, 64);
                v[u] = *(const uint2*)(feat + (size_t)s * D + lane * 4);
            }
            #pragma unroll
            for (int u = 0; u < 8; ++u) {
                acc[0] += bflo(v[u].x); acc[1] += bfhi(v[u].x);
                acc[2] += bflo(v[u].y); acc[3] += bfhi(v[u].y);
            }
        }
    }
    for (; j < stored; ++j) {
        int s = __shfl(myIdx, j, 64);
        if constexpr (VPL == 2) {
            unsigned v = *(const unsigned*)(feat + (size_t)s * D + lane * 2);
            acc[0] += bflo(v); acc[1] += bfhi(v);
        } else {
            uint2 v = *(const uint2*)(feat + (size_t)s * D + lane * 4);
            acc[0] += bflo(v.x); acc[1] += bfhi(v.x);
            acc[2] += bflo(v.y); acc[3] += bfhi(v.y);
        }
    }

    float invd = 1.0f / (float)(deg > 0 ? deg : 1);  // true-degree divisor
    if constexpr (VPL == 2) {
        unsigned o = (unsigned)f2bf(acc[0] * invd) | ((unsigned)f2bf(acc[1] * invd) << 16);
        __builtin_nontemporal_store(o, (unsigned*)(out + (size_t)wave * D + lane * 2));
    } else {
        unsigned lo = (unsigned)f2bf(acc[0] * invd) | ((unsigned)f2bf(acc[1] * invd) << 16);
        unsigned hi = (unsigned)f2bf(acc[2] * invd) | ((unsigned)f2bf(acc[3] * invd) << 16);
        unsigned long long o = (unsigned long long)lo | ((unsigned long long)hi << 32);
        __builtin_nontemporal_store(o, (unsigned long long*)(out + (size_t)wave * D + lane * 4));
    }
}

// ---------------- bf16 MFMA GEMM + bias + ReLU ----------------
// MODE 0: store bf16 to Cb.  MODE 1: fused per-graph-sum (sorted gids).
// Lanes {m, m+16, m+32, m+48} of a wave hold the 4 quadrant partials of the
// SAME output column -> shfl_xor(16/32) reduces them in-register; loop over
// the (usually 1) graphs present in the 64 sorted rows -> one atomicAdd per
// (col, graph) per block.

template <int K, int MODE>
__launch_bounds__(256)
__global__ void gemm_mfma_kernel(const unsigned short* __restrict__ A,
                                 const unsigned short* __restrict__ Wt,
                                 const float* __restrict__ bias,
                                 unsigned short* __restrict__ Cb,
                                 const int* __restrict__ gids,
                                 float* __restrict__ gsum,
                                 int N) {
    constexpr int LDS = 40;
    __shared__ unsigned short As[64 * LDS];
    __shared__ unsigned short Bs[256 * LDS];

    int tid = threadIdx.x;
    int wave = tid >> 6;
    int lane = tid & 63;
    int m = lane & 15;
    int q = lane >> 4;
    int rowBase = blockIdx.x * 64;

    f32x4 acc[4][4] = {};

    for (int kc = 0; kc < K; kc += 32) {
        {
            int r = tid >> 2;
            int seg = tid & 3;
            int gr = rowBase + r;
            uint4 v = make_uint4(0, 0, 0, 0);
            if (gr < N) v = *(const uint4*)(A + (size_t)gr * K + kc + seg * 8);
            *(uint4*)&As[r * LDS + seg * 8] = v;
        }
        #pragma unroll
        for (int it = 0; it < 4; ++it) {
            int n = (tid >> 2) + it * 64;
            int seg = tid & 3;
            uint4 v = *(const uint4*)(Wt + (size_t)n * K + kc + seg * 8);
            *(uint4*)&Bs[n * LDS + seg * 8] = v;
        }
        __syncthreads();

        bf16x8 af[4], bfr[4];
        #pragma unroll
        for (int r = 0; r < 4; ++r)
            af[r] = *(const bf16x8*)&As[(r * 16 + m) * LDS + q * 8];
        #pragma unroll
        for (int c = 0; c < 4; ++c)
            bfr[c] = *(const bf16x8*)&Bs[(wave * 64 + c * 16 + m) * LDS + q * 8];
        #pragma unroll
        for (int r = 0; r < 4; ++r)
            #pragma unroll
            for (int c = 0; c < 4; ++c)
                acc[r][c] = __builtin_amdgcn_mfma_f32_16x16x32_bf16(af[r], bfr[c], acc[r][c], 0, 0, 0);
        __syncthreads();
    }

    if constexpr (MODE == 0) {
        #pragma unroll
        for (int c = 0; c < 4; ++c) {
            int col = wave * 64 + c * 16 + m;
            float bv = bias[col];
            #pragma unroll
            for (int r = 0; r < 4; ++r) {
                #pragma unroll
                for (int reg = 0; reg < 4; ++reg) {
                    int grow = rowBase + r * 16 + q * 4 + reg;
                    if (grow < N)
                        Cb[(size_t)grow * 256 + col] = f2bf(fmaxf(acc[r][c][reg] + bv, 0.0f));
                }
            }
        }
    } else {
        int* sgid = (int*)As;
        if (tid < 64) {
            int gr = rowBase + tid;
            sgid[tid] = (gr < N) ? gids[gr] : 0x7fffffff;
        }
        __syncthreads();
        int lastValid = N - 1 - rowBase;
        if (lastValid > 63) lastValid = 63;
        int gmin = sgid[0];
        int gmax = sgid[lastValid];
        #pragma unroll
        for (int c = 0; c < 4; ++c) {
            int col = wave * 64 + c * 16 + m;
            float bv = bias[col];
            for (int g = gmin; g <= gmax; ++g) {
                float p = 0.0f;
                #pragma unroll
                for (int r = 0; r < 4; ++r) {
                    #pragma unroll
                    for (int reg = 0; reg < 4; ++reg) {
                        int lr = r * 16 + q * 4 + reg;
                        if (sgid[lr] == g)
                            p += fmaxf(acc[r][c][reg] + bv, 0.0f);
                    }
                }
                p += __shfl_xor(p, 16, 64);
                p += __shfl_xor(p, 32, 64);
                if (q == 0 && p != 0.0f)
                    atomicAdd(&gsum[g * 256 + col], p);
            }
        }
    }
}

// ---------------- MLP head ----------------
// 512 threads: 4-way k-split (j = t&127, kq = t>>7 handles 64 ks) + LDS
// combine. 8 waves/CU: the 64-deep Wr1 load chain gets hidden.

__global__ void final_kernel(const float* __restrict__ gsum, const int* __restrict__ gstart,
                             const float* __restrict__ Wr1, const float* __restrict__ br1,
                             const float* __restrict__ Wr2, const float* __restrict__ br2,
                             float* __restrict__ out) {
    __shared__ float part[512];
    __shared__ float ws2[2];
    int g = blockIdx.x;
    int t = threadIdx.x;  // 512
    int j = t & 127;
    int kq = t >> 7;
    int c = gstart[g + 1] - gstart[g];
    float invc = 1.0f / (float)(c > 0 ? c : 1);
    const float* gs = gsum + g * 256;
    float acc = 0.0f;
    #pragma unroll 8
    for (int k = kq * 64; k < kq * 64 + 64; ++k)
        acc += gs[k] * Wr1[k * 128 + j];
    part[t] = acc;
    __syncthreads();
    if (t < 128) {
        float s = part[j] + part[128 + j] + part[256 + j] + part[384 + j];
        float p = (s * invc + br1[j]) * Wr2[j];
        #pragma unroll
        for (int d = 32; d > 0; d >>= 1) p += __shfl_down(p, d, 64);
        if ((t & 63) == 0) ws2[t >> 6] = p;
    }
    __syncthreads();
    if (t == 0) out[g] = ws2[0] + ws2[1] + br2[0];
}

// ---------------- launch ----------------

extern "C" void kernel_launch(void* const* d_in, const int* in_sizes, int n_in,
                              void* d_out, int out_size, void* d_ws, size_t ws_size,
                              hipStream_t stream) {
    const float* h    = (const float*)d_in[0];
    const int*   src  = (const int*)d_in[1];
    const int*   dst  = (const int*)d_in[2];
    const int*   gids = (const int*)d_in[3];
    const float* W1   = (const float*)d_in[4];
    const float* b1   = (const float*)d_in[5];
    const float* W2   = (const float*)d_in[6];
    const float* b2   = (const float*)d_in[7];
    const float* Wr1  = (const float*)d_in[8];
    const float* br1  = (const float*)d_in[9];
    const float* Wr2  = (const float*)d_in[10];
    const float* br2  = (const float*)d_in[11];

    int N = in_sizes[0] / 128;
    int E = in_sizes[1];
    int ngrp = (N + 511) >> GSHIFT;  // 98 for N=50000 (must be <= 128)

    // workspace ([gsum|cursor] contiguous for a single memset)
    char* w = (char*)d_ws;
    unsigned short* hb     = (unsigned short*)w;  w += (size_t)N * 128 * sizeof(unsigned short);
    unsigned short* h1b    = (unsigned short*)w;  w += (size_t)N * 256 * sizeof(unsigned short);
    unsigned short* aggOut = (unsigned short*)w;  w += (size_t)N * 256 * sizeof(unsigned short);
    int* cnt    = (int*)w;              w += (size_t)N * sizeof(int);
    float* gsum = (float*)w;            w += (size_t)NUM_GRAPHS * 256 * sizeof(float);
    int* cursor = (int*)w;              w += 128 * sizeof(int);
    unsigned short* eidx = (unsigned short*)w;  w += (size_t)N * MAXDEG * sizeof(unsigned short);
    unsigned short* Wt1 = (unsigned short*)w;   w += 256 * 128 * sizeof(unsigned short);
    unsigned short* Wt2 = (unsigned short*)w;   w += 256 * 256 * sizeof(unsigned short);
    int* gstart = (int*)w;              w += (size_t)(NUM_GRAPHS + 1) * sizeof(int);
    // partE aliases aggOut: partE live = dispatches 2-3, aggOut live from 4 on.
    // (4.7MB < 25.6MB; keeps total workspace at R20's proven footprint)
    unsigned* partE = (unsigned*)aggOut;

    // 1) zero gsum+cursor in one shot (cnt fully written by build_kernel)
    hipMemsetAsync(gsum, 0,
                   (size_t)NUM_GRAPHS * 256 * sizeof(float) + 128 * sizeof(int),
                   stream);
    // 2) prep: edge partition (group-binned), gstart, h cast, weight transposes
    misc_kernel<<<MISC_NB, 256, 0, stream>>>(dst, src, gids, h, W1, W2, cursor, partE,
                                             gstart, hb, Wt1, Wt2, N, E);
    // 3) ELL build: per-group LDS rank atomics, single-writer eidx regions
    build_kernel<<<ngrp, 256, 0, stream>>>(partE, cursor, cnt, eidx, N);

    // 4-5) layer 1
    agg_mean_bf16_kernel<128><<<(N + 3) / 4, 256, 0, stream>>>(hb, cnt, eidx, aggOut, N);
    gemm_mfma_kernel<128, 0><<<(N + 63) / 64, 256, 0, stream>>>(aggOut, Wt1, b1, h1b, nullptr, nullptr, N);

    // 6-7) layer 2 (readout fused into GEMM epilogue)
    agg_mean_bf16_kernel<256><<<(N + 3) / 4, 256, 0, stream>>>(h1b, cnt, eidx, aggOut, N);
    gemm_mfma_kernel<256, 1><<<(N + 63) / 64, 256, 0, stream>>>(aggOut, Wt2, b2, nullptr, gids, gsum, N);

    // 8) head
    final_kernel<<<NUM_GRAPHS, 512, 0, stream>>>(gsum, gstart, Wr1, br1, Wr2, br2, (float*)d_out);
}

// Round 10
// 279.633 us; speedup vs baseline: 1.0253x; 1.0253x over previous
//
#include <hip/hip_runtime.h>

// GCN regressor: 2x (mean-aggregate + linear+ReLU) + per-graph mean + MLP head.
// N=50000 nodes, E=800000 edges, D_IN=128, H1=256, H2=128, G=256.
// R24 = R23 resubmit (compile fix: __builtin_nontemporal_store needs a clang
// vector type, not HIP's uint4 class -> u32x4 ext_vector_type in the flush).
// R23: coalesce-everything ELL build (R21/R22 was neutral because it only
// MOVED the 800K scattered ~4B writes: partE scatter ~30us + build eidx
// scatter ~25us =~ R20's atomic scatter. Invariant learned: any 800K-element
// 4B-granule scatter costs ~30us at the ~25G trans/s service rate; the only
// fix is coarser writes):
//  - misc partition: block-local LDS compaction (hist -> Kogge-Stone scan ->
//    LDS scatter into group-ordered comp[] -> binary-search flush with
//    CONSECUTIVE global addresses per run). Global writes ~60K transactions.
//  - build: 256-node groups (196 blocks); whole ELL tile (256x64x2B = 32KB)
//    staged in LDS; rank scatter is LDS-local; global flush = 32KB u32x4
//    stream. eidx padded to ngrp*256 rows so flush needs no guard.
// AGGS ARE CLOSED (evidence, 5 structural probes, all 54-58us):
//  - R16 eidx-chain hoist: -2.6us. R17/R18 16B/lane + deep bursts: null.
//  - R19 feature-half XCD sharding: FETCH 173->147MB but time +4%.
//  => bound = random-line SERVICE rate, not HBM bytes/issue depth/footprint.
// Closed experiments (do not revisit):
//  - R6 chunked XCD-local gather: 7x. R8/R9 grid.sync: 2x. R11 agg-GEMM
//    fusion: occupancy collapse. R13 dispatch-merge: neutral. R17
//    launch_bounds(256,8): scratch spill. R20 per-edge global-atomic ELL
//    build: 55-62us. R21/R22 scattered partE+build writes: neutral.

#define NUM_GRAPHS 256
#define MAXDEG 64
#define GSHIFT 8              // 256-node groups
#define GCAP 4864             // per-group edge capacity (mean 4082, +12 sigma)
#define CHUNK_MAX 3200        // per-block edge chunk cap (E=800000/256 = 3125)

// misc_kernel block partition
#define PART_B0 0
#define PART_NB 256
#define CST_B0 (PART_B0 + PART_NB)
#define CST_NB 512
#define GST_B0 (CST_B0 + CST_NB)
#define GST_NB 64
#define WT1_B0 (GST_B0 + GST_NB)
#define WT1_NB 16
#define WT2_B0 (WT1_B0 + WT1_NB)
#define WT2_NB 32
#define MISC_NB (WT2_B0 + WT2_NB)

typedef __attribute__((ext_vector_type(8))) short bf16x8;
typedef __attribute__((ext_vector_type(4))) float f32x4;
typedef __attribute__((ext_vector_type(4))) unsigned int u32x4;

__device__ inline unsigned short f2bf(float f) {  // round-to-nearest-even
    unsigned u = __float_as_uint(f);
    return (unsigned short)((u + 0x7fff + ((u >> 16) & 1)) >> 16);
}
__device__ inline float bflo(unsigned u) { return __uint_as_float(u << 16); }
__device__ inline float bfhi(unsigned u) { return __uint_as_float(u & 0xffff0000u); }

// ---------------- misc: edge partition (compacted) + gstart + h cast + weight transposes ----------------

__launch_bounds__(256)
__global__ void misc_kernel(const int* __restrict__ dst, const int* __restrict__ src,
                            const int* __restrict__ gids,
                            const float* __restrict__ h,
                            const float* __restrict__ W1, const float* __restrict__ W2,
                            int* __restrict__ cursor, unsigned* __restrict__ partE,
                            int* __restrict__ gstart,
                            unsigned short* __restrict__ hb,
                            unsigned short* __restrict__ Wt1, unsigned short* __restrict__ Wt2,
                            int N, int E) {
    int b = blockIdx.x, tid = threadIdx.x;
    if (b < CST_B0) {  // partition: hist -> scan -> LDS compaction -> coalesced flush
        __shared__ unsigned lcnt[256];
        __shared__ unsigned sbuf[256];
        __shared__ unsigned lbase[257];
        __shared__ unsigned gb[256];
        __shared__ unsigned comp[CHUNK_MAX];
        int b0 = b - PART_B0;
        int chunk = (E + PART_NB - 1) / PART_NB;
        int ebeg = b0 * chunk;
        int eend = ebeg + chunk; if (eend > E) eend = E;
        int ecount = eend - ebeg; if (ecount < 0) ecount = 0;

        lcnt[tid] = 0;
        __syncthreads();
        for (int e = ebeg + tid; e < eend; e += 256) {
            int d = __builtin_nontemporal_load(&dst[e]);
            atomicAdd(&lcnt[d >> GSHIFT], 1u);
        }
        __syncthreads();
        // Kogge-Stone inclusive scan over 256 bins -> exclusive lbase
        unsigned v = lcnt[tid];
        sbuf[tid] = v;
        __syncthreads();
        #pragma unroll
        for (int dd = 1; dd < 256; dd <<= 1) {
            unsigned t = (tid >= dd) ? sbuf[tid - dd] : 0u;
            __syncthreads();
            sbuf[tid] += t;
            __syncthreads();
        }
        lbase[tid] = sbuf[tid] - v;
        if (tid == 255) lbase[256] = sbuf[255];
        // claim global run per non-empty group; reset lcnt for sweep 2
        gb[tid] = v ? (unsigned)atomicAdd(&cursor[tid], (int)v) : 0u;
        lcnt[tid] = 0;
        __syncthreads();
        // sweep 2: LDS scatter into group-ordered compacted buffer
        for (int e = ebeg + tid; e < eend; e += 256) {
            int d = __builtin_nontemporal_load(&dst[e]);
            int s = __builtin_nontemporal_load(&src[e]);
            int g = d >> GSHIFT;
            unsigned r = atomicAdd(&lcnt[g], 1u) + lbase[g];
            if (r < (unsigned)CHUNK_MAX)  // always true for E=800000
                comp[r] = ((unsigned)s << GSHIFT) | (unsigned)(d & 255);
        }
        __syncthreads();
        // coalesced flush: consecutive i in a run -> consecutive global addrs
        for (int i = tid; i < ecount; i += 256) {
            int lo = 0, hi = 256;
            while (hi - lo > 1) {  // find g: lbase[g] <= i < lbase[g+1]
                int mid = (lo + hi) >> 1;
                if (lbase[mid] <= (unsigned)i) lo = mid; else hi = mid;
            }
            unsigned dest = (unsigned)lo * GCAP + gb[lo] + ((unsigned)i - lbase[lo]);
            if (dest < (unsigned)(256 * GCAP))
                __builtin_nontemporal_store(comp[i], &partE[dest]);
        }
    } else if (b < GST_B0) {  // cast h -> bf16 (float4 granules)
        int lid = (b - CST_B0) * 256 + tid;
        int total4 = N * 32;
        for (int i = lid; i < total4; i += CST_NB * 256) {
            float4 v = *(const float4*)(h + (size_t)i * 4);
            ushort4 o;
            o.x = f2bf(v.x); o.y = f2bf(v.y); o.z = f2bf(v.z); o.w = f2bf(v.w);
            *(ushort4*)(hb + (size_t)i * 4) = o;
        }
    } else if (b < WT1_B0) {  // graph segment starts (gids sorted)
        int lid = (b - GST_B0) * 256 + tid;
        for (int n = lid; n < N; n += GST_NB * 256) {
            int g = gids[n];
            int gp = (n == 0) ? -1 : gids[n - 1];
            for (int x = gp + 1; x <= g; ++x) gstart[x] = n;
            if (n == N - 1)
                for (int x = g + 1; x <= NUM_GRAPHS; ++x) gstart[x] = N;
        }
    } else if (b < WT2_B0) {  // Wt1[n][k] = bf16(W1[k][n]), K=128
        int lid = (b - WT1_B0) * 256 + tid;
        for (int i = lid; i < 256 * 128; i += WT1_NB * 256)
            Wt1[i] = f2bf(W1[(size_t)(i & 127) * 256 + (i >> 7)]);
    } else {  // Wt2[n][k] = bf16(W2[k][n]), K=256
        int lid = (b - WT2_B0) * 256 + tid;
        for (int i = lid; i < 256 * 256; i += WT2_NB * 256)
            Wt2[i] = f2bf(W2[(size_t)(i & 255) * 256 + (i >> 8)]);
    }
}

// ---------------- ELL build: 256-node groups, full tile staged in LDS ----------------
// Rank scatter is LDS-local (32KB tile); global flush is a straight u32x4
// stream (fully coalesced). No scattered global writes anywhere.

__launch_bounds__(256)
__global__ void build_kernel(const unsigned* __restrict__ partE,
                             const int* __restrict__ cursor,
                             int* __restrict__ cnt, unsigned short* __restrict__ eidx,
                             int N) {
    __shared__ unsigned short es[256 * MAXDEG];  // 32KB ELL tile
    __shared__ unsigned hist[256];
    int g = blockIdx.x, tid = threadIdx.x;
    hist[tid] = 0;
    __syncthreads();
    int ec = cursor[g]; if (ec > GCAP) ec = GCAP;
    const unsigned* pe = partE + (size_t)g * GCAP;
    for (int i = tid; i < ec; i += 256) {
        unsigned p = pe[i];
        int dl = (int)(p & 255);
        int s = (int)(p >> GSHIFT);
        unsigned r = atomicAdd(&hist[dl], 1u);
        if (r < MAXDEG)  // statistically unreachable (max deg ~40)
            es[dl * MAXDEG + r] = (unsigned short)s;
    }
    __syncthreads();
    // flush: 256 rows x 128B = 2048 x 16B (eidx padded to ngrp*256 rows)
    const u32x4* s4 = (const u32x4*)es;
    u32x4* d4 = (u32x4*)(eidx + ((size_t)g << GSHIFT) * MAXDEG);
    for (int i = tid; i < 2048; i += 256)
        __builtin_nontemporal_store(s4[i], &d4[i]);
    int node = (g << GSHIFT) + tid;
    if (node < N) cnt[node] = (int)hist[tid];
}

// ---------------- mean aggregation: one wave per dst node, ELL edge table ----------------
// R16-exact gather loop (best measured: 54.3us agg256). Coalesced per-lane
// eidx load + shfl broadcast; 4B/8B row loads (economy proven null R17/R18).
// NT output store: consumer (GEMM) streams it; keep L2 for the gather table.

template <int D>
__global__ void agg_mean_bf16_kernel(const unsigned short* __restrict__ feat,
                                     const int* __restrict__ cnt,
                                     const unsigned short* __restrict__ eidx,
                                     unsigned short* __restrict__ out, int N) {
    constexpr int VPL = D / 64;  // 2 or 4
    int wave = blockIdx.x * (blockDim.x >> 6) + (threadIdx.x >> 6);
    int lane = threadIdx.x & 63;
    if (wave >= N) return;
    int deg = cnt[wave];
    int stored = deg > MAXDEG ? MAXDEG : deg;
    const unsigned short* row = eidx + (size_t)wave * MAXDEG;
    int myIdx = (lane < stored) ? (int)row[lane] : 0;

    float acc[VPL];
    #pragma unroll
    for (int i = 0; i < VPL; ++i) acc[i] = 0.0f;

    int j = 0;
    for (; j + 8 <= stored; j += 8) {
        if constexpr (VPL == 2) {
            unsigned v[8];
            #pragma unroll
            for (int u = 0; u < 8; ++u) {
                int s = __shfl(myIdx, j + u, 64);
                v[u] = *(const unsigned*)(feat + (size_t)s * D + lane * 2);
            }
            #pragma unroll
            for (int u = 0; u < 8; ++u) { acc[0] += bflo(v[u]); acc[1] += bfhi(v[u]); }
        } else {
            uint2 v[8];
            #pragma unroll
            for (int u = 0; u < 8; ++u) {
                int s = __shfl(myIdx, j + u, 64);
                v[u] = *(const uint2*)(feat + (size_t)s * D + lane * 4);
            }
            #pragma unroll
            for (int u = 0; u < 8; ++u) {
                acc[0] += bflo(v[u].x); acc[1] += bfhi(v[u].x);
                acc[2] += bflo(v[u].y); acc[3] += bfhi(v[u].y);
            }
        }
    }
    for (; j < stored; ++j) {
        int s = __shfl(myIdx, j, 64);
        if constexpr (VPL == 2) {
            unsigned v = *(const unsigned*)(feat + (size_t)s * D + lane * 2);
            acc[0] += bflo(v); acc[1] += bfhi(v);
        } else {
            uint2 v = *(const uint2*)(feat + (size_t)s * D + lane * 4);
            acc[0] += bflo(v.x); acc[1] += bfhi(v.x);
            acc[2] += bflo(v.y); acc[3] += bfhi(v.y);
        }
    }

    float invd = 1.0f / (float)(deg > 0 ? deg : 1);  // true-degree divisor
    if constexpr (VPL == 2) {
        unsigned o = (unsigned)f2bf(acc[0] * invd) | ((unsigned)f2bf(acc[1] * invd) << 16);
        __builtin_nontemporal_store(o, (unsigned*)(out + (size_t)wave * D + lane * 2));
    } else {
        unsigned lo = (unsigned)f2bf(acc[0] * invd) | ((unsigned)f2bf(acc[1] * invd) << 16);
        unsigned hi = (unsigned)f2bf(acc[2] * invd) | ((unsigned)f2bf(acc[3] * invd) << 16);
        unsigned long long o = (unsigned long long)lo | ((unsigned long long)hi << 32);
        __builtin_nontemporal_store(o, (unsigned long long*)(out + (size_t)wave * D + lane * 4));
    }
}

// ---------------- bf16 MFMA GEMM + bias + ReLU ----------------
// MODE 0: store bf16 to Cb.  MODE 1: fused per-graph-sum (sorted gids).
// Lanes {m, m+16, m+32, m+48} of a wave hold the 4 quadrant partials of the
// SAME output column -> shfl_xor(16/32) reduces them in-register; loop over
// the (usually 1) graphs present in the 64 sorted rows -> one atomicAdd per
// (col, graph) per block.

template <int K, int MODE>
__launch_bounds__(256)
__global__ void gemm_mfma_kernel(const unsigned short* __restrict__ A,
                                 const unsigned short* __restrict__ Wt,
                                 const float* __restrict__ bias,
                                 unsigned short* __restrict__ Cb,
                                 const int* __restrict__ gids,
                                 float* __restrict__ gsum,
                                 int N) {
    constexpr int LDS = 40;
    __shared__ unsigned short As[64 * LDS];
    __shared__ unsigned short Bs[256 * LDS];

    int tid = threadIdx.x;
    int wave = tid >> 6;
    int lane = tid & 63;
    int m = lane & 15;
    int q = lane >> 4;
    int rowBase = blockIdx.x * 64;

    f32x4 acc[4][4] = {};

    for (int kc = 0; kc < K; kc += 32) {
        {
            int r = tid >> 2;
            int seg = tid & 3;
            int gr = rowBase + r;
            uint4 v = make_uint4(0, 0, 0, 0);
            if (gr < N) v = *(const uint4*)(A + (size_t)gr * K + kc + seg * 8);
            *(uint4*)&As[r * LDS + seg * 8] = v;
        }
        #pragma unroll
        for (int it = 0; it < 4; ++it) {
            int n = (tid >> 2) + it * 64;
            int seg = tid & 3;
            uint4 v = *(const uint4*)(Wt + (size_t)n * K + kc + seg * 8);
            *(uint4*)&Bs[n * LDS + seg * 8] = v;
        }
        __syncthreads();

        bf16x8 af[4], bfr[4];
        #pragma unroll
        for (int r = 0; r < 4; ++r)
            af[r] = *(const bf16x8*)&As[(r * 16 + m) * LDS + q * 8];
        #pragma unroll
        for (int c = 0; c < 4; ++c)
            bfr[c] = *(const bf16x8*)&Bs[(wave * 64 + c * 16 + m) * LDS + q * 8];
        #pragma unroll
        for (int r = 0; r < 4; ++r)
            #pragma unroll
            for (int c = 0; c < 4; ++c)
                acc[r][c] = __builtin_amdgcn_mfma_f32_16x16x32_bf16(af[r], bfr[c], acc[r][c], 0, 0, 0);
        __syncthreads();
    }

    if constexpr (MODE == 0) {
        #pragma unroll
        for (int c = 0; c < 4; ++c) {
            int col = wave * 64 + c * 16 + m;
            float bv = bias[col];
            #pragma unroll
            for (int r = 0; r < 4; ++r) {
                #pragma unroll
                for (int reg = 0; reg < 4; ++reg) {
                    int grow = rowBase + r * 16 + q * 4 + reg;
                    if (grow < N)
                        Cb[(size_t)grow * 256 + col] = f2bf(fmaxf(acc[r][c][reg] + bv, 0.0f));
                }
            }
        }
    } else {
        int* sgid = (int*)As;
        if (tid < 64) {
            int gr = rowBase + tid;
            sgid[tid] = (gr < N) ? gids[gr] : 0x7fffffff;
        }
        __syncthreads();
        int lastValid = N - 1 - rowBase;
        if (lastValid > 63) lastValid = 63;
        int gmin = sgid[0];
        int gmax = sgid[lastValid];
        #pragma unroll
        for (int c = 0; c < 4; ++c) {
            int col = wave * 64 + c * 16 + m;
            float bv = bias[col];
            for (int g = gmin; g <= gmax; ++g) {
                float p = 0.0f;
                #pragma unroll
                for (int r = 0; r < 4; ++r) {
                    #pragma unroll
                    for (int reg = 0; reg < 4; ++reg) {
                        int lr = r * 16 + q * 4 + reg;
                        if (sgid[lr] == g)
                            p += fmaxf(acc[r][c][reg] + bv, 0.0f);
                    }
                }
                p += __shfl_xor(p, 16, 64);
                p += __shfl_xor(p, 32, 64);
                if (q == 0 && p != 0.0f)
                    atomicAdd(&gsum[g * 256 + col], p);
            }
        }
    }
}

// ---------------- MLP head ----------------
// 512 threads: 4-way k-split (j = t&127, kq = t>>7 handles 64 ks) + LDS
// combine. 8 waves/CU: the 64-deep Wr1 load chain gets hidden.

__global__ void final_kernel(const float* __restrict__ gsum, const int* __restrict__ gstart,
                             const float* __restrict__ Wr1, const float* __restrict__ br1,
                             const float* __restrict__ Wr2, const float* __restrict__ br2,
                             float* __restrict__ out) {
    __shared__ float part[512];
    __shared__ float ws2[2];
    int g = blockIdx.x;
    int t = threadIdx.x;  // 512
    int j = t & 127;
    int kq = t >> 7;
    int c = gstart[g + 1] - gstart[g];
    float invc = 1.0f / (float)(c > 0 ? c : 1);
    const float* gs = gsum + g * 256;
    float acc = 0.0f;
    #pragma unroll 8
    for (int k = kq * 64; k < kq * 64 + 64; ++k)
        acc += gs[k] * Wr1[k * 128 + j];
    part[t] = acc;
    __syncthreads();
    if (t < 128) {
        float s = part[j] + part[128 + j] + part[256 + j] + part[384 + j];
        float p = (s * invc + br1[j]) * Wr2[j];
        #pragma unroll
        for (int d = 32; d > 0; d >>= 1) p += __shfl_down(p, d, 64);
        if ((t & 63) == 0) ws2[t >> 6] = p;
    }
    __syncthreads();
    if (t == 0) out[g] = ws2[0] + ws2[1] + br2[0];
}

// ---------------- launch ----------------

extern "C" void kernel_launch(void* const* d_in, const int* in_sizes, int n_in,
                              void* d_out, int out_size, void* d_ws, size_t ws_size,
                              hipStream_t stream) {
    const float* h    = (const float*)d_in[0];
    const int*   src  = (const int*)d_in[1];
    const int*   dst  = (const int*)d_in[2];
    const int*   gids = (const int*)d_in[3];
    const float* W1   = (const float*)d_in[4];
    const float* b1   = (const float*)d_in[5];
    const float* W2   = (const float*)d_in[6];
    const float* b2   = (const float*)d_in[7];
    const float* Wr1  = (const float*)d_in[8];
    const float* br1  = (const float*)d_in[9];
    const float* Wr2  = (const float*)d_in[10];
    const float* br2  = (const float*)d_in[11];

    int N = in_sizes[0] / 128;
    int E = in_sizes[1];
    int ngrp = (N + 255) >> GSHIFT;  // 196 for N=50000 (must be <= 256)

    // workspace ([gsum|cursor] contiguous for a single memset)
    char* w = (char*)d_ws;
    unsigned short* hb     = (unsigned short*)w;  w += (size_t)N * 128 * sizeof(unsigned short);
    unsigned short* h1b    = (unsigned short*)w;  w += (size_t)N * 256 * sizeof(unsigned short);
    unsigned short* aggOut = (unsigned short*)w;  w += (size_t)N * 256 * sizeof(unsigned short);
    int* cnt    = (int*)w;              w += (size_t)N * sizeof(int);
    float* gsum = (float*)w;            w += (size_t)NUM_GRAPHS * 256 * sizeof(float);
    int* cursor = (int*)w;              w += 256 * sizeof(int);
    unsigned short* eidx = (unsigned short*)w;  w += (size_t)ngrp * 256 * MAXDEG * sizeof(unsigned short);
    unsigned short* Wt1 = (unsigned short*)w;   w += 256 * 128 * sizeof(unsigned short);
    unsigned short* Wt2 = (unsigned short*)w;   w += 256 * 256 * sizeof(unsigned short);
    int* gstart = (int*)w;              w += (size_t)(NUM_GRAPHS + 1) * sizeof(int);
    // partE aliases aggOut: partE live = dispatches 2-3, aggOut live from 4 on.
    // (256*GCAP*4B = 4.98MB < 25.6MB)
    unsigned* partE = (unsigned*)aggOut;

    // 1) zero gsum+cursor in one shot (cnt fully written by build_kernel)
    (void)hipMemsetAsync(gsum, 0,
                         (size_t)NUM_GRAPHS * 256 * sizeof(float) + 256 * sizeof(int),
                         stream);
    // 2) prep: compacted edge partition, gstart, h cast, weight transposes
    misc_kernel<<<MISC_NB, 256, 0, stream>>>(dst, src, gids, h, W1, W2, cursor, partE,
                                             gstart, hb, Wt1, Wt2, N, E);
    // 3) ELL build: LDS-staged tile, fully-coalesced global writes
    build_kernel<<<ngrp, 256, 0, stream>>>(partE, cursor, cnt, eidx, N);

    // 4-5) layer 1
    agg_mean_bf16_kernel<128><<<(N + 3) / 4, 256, 0, stream>>>(hb, cnt, eidx, aggOut, N);
    gemm_mfma_kernel<128, 0><<<(N + 63) / 64, 256, 0, stream>>>(aggOut, Wt1, b1, h1b, nullptr, nullptr, N);

    // 6-7) layer 2 (readout fused into GEMM epilogue)
    agg_mean_bf16_kernel<256><<<(N + 3) / 4, 256, 0, stream>>>(h1b, cnt, eidx, aggOut, N);
    gemm_mfma_kernel<256, 1><<<(N + 63) / 64, 256, 0, stream>>>(aggOut, Wt2, b2, nullptr, gids, gsum, N);

    // 8) head
    final_kernel<<<NUM_GRAPHS, 512, 0, stream>>>(gsum, gstart, Wr1, br1, Wr2, br2, (float*)d_out);
}